// Round 2
// baseline (456.279 us; speedup 1.0000x reference)
//
#include <hip/hip_runtime.h>

// Problem constants (from reference)
#define BATCH 1024
#define NL    64
#define NH    32
#define NG    20000
#define NC    64
#define GOI   1000

typedef __attribute__((ext_vector_type(8))) short  short8;
typedef __attribute__((ext_vector_type(4))) float  f32x4;

static __device__ __forceinline__ unsigned short f2bf(float f) {
    unsigned int u = __builtin_bit_cast(unsigned int, f);
    // round-to-nearest-even
    unsigned int r = (u + 0x7fffu + ((u >> 16) & 1u)) >> 16;
    return (unsigned short)r;
}

// ---------------------------------------------------------------------------
// Stage 1: h = relu(bn(latent @ W + b))  (fp32 math) -> bf16 [BATCH][NH] in ws
// ---------------------------------------------------------------------------
__global__ __launch_bounds__(256) void h_kernel(
    const float* __restrict__ latent,  // [BATCH][NL] fp32
    const float* __restrict__ W,       // [NL][NH]   fp32
    const float* __restrict__ bias,    // [NH]
    const float* __restrict__ gamma,   // [NH]
    const float* __restrict__ beta,    // [NH]
    const float* __restrict__ mean,    // [NH]
    const float* __restrict__ var,     // [NH]
    unsigned short* __restrict__ h)    // [BATCH][NH] bf16
{
    int tid = blockIdx.x * 256 + threadIdx.x;   // 0 .. BATCH*NH-1
    int b = tid >> 5;
    int k = tid & 31;
    float acc = 0.f;
    #pragma unroll 8
    for (int j = 0; j < NL; ++j)
        acc += latent[b * NL + j] * W[j * NH + k];
    acc += bias[k];
    float x = (acc - mean[k]) * rsqrtf(var[k] + 1e-5f) * gamma[k] + beta[k];
    x = fmaxf(x, 0.f);
    h[tid] = f2bf(x);
}

// ---------------------------------------------------------------------------
// Stage 2: logit[b,g,c] = sum_k h[b,k] * logit_table[genes[g], k, c]
// One gene per blockIdx.x; 4 waves; each wave: 16 batches x 64 c per iter
// (4 MFMAs, full K=32), 4 iters. blockIdx.y quarters the batch dim.
// Table gathered in fp32, converted to bf16 fragments; accumulate fp32.
// ---------------------------------------------------------------------------
__global__ __launch_bounds__(256) void logit_kernel(
    const unsigned short* __restrict__ h,      // [BATCH][NH] bf16 (ws)
    const float*          __restrict__ table,  // [NG][NH][NC] fp32
    const int*            __restrict__ genes,  // [GOI] int32
    float*                __restrict__ out)    // [BATCH][GOI][NC] fp32
{
    const int g    = blockIdx.x;
    const int wave = threadIdx.x >> 6;
    const int lane = threadIdx.x & 63;
    const int l15  = lane & 15;
    const int quad = lane >> 4;

    const long long gene = (long long)genes[g];
    const float* lw = table + gene * (long long)(NH * NC);

    // B fragments: tile t covers c = t*16 .. t*16+15.
    // B[k][n]: lane holds n = l15, k = quad*8 + j  (j = 0..7)
    short8 bf[4];
    #pragma unroll
    for (int t = 0; t < 4; ++t) {
        #pragma unroll
        for (int j = 0; j < 8; ++j)
            bf[t][j] = (short)f2bf(lw[(quad * 8 + j) * NC + t * 16 + l15]);
    }

    #pragma unroll
    for (int it = 0; it < 4; ++it) {
        const int b0 = blockIdx.y * 256 + it * 64 + wave * 16;
        // A fragment: A[m][k], m = l15 (batch row), k = quad*8 + j -> 16B load
        short8 af = *(const short8*)(h + (b0 + l15) * NH + quad * 8);
        #pragma unroll
        for (int t = 0; t < 4; ++t) {
            f32x4 acc = {0.f, 0.f, 0.f, 0.f};
            acc = __builtin_amdgcn_mfma_f32_16x16x32_bf16(af, bf[t], acc, 0, 0, 0);
            // C/D layout: col = l15, row = quad*4 + r
            #pragma unroll
            for (int r = 0; r < 4; ++r) {
                int b = b0 + quad * 4 + r;
                out[((long long)b * GOI + g) * NC + t * 16 + l15] = acc[r];
            }
        }
    }
}

// ---------------------------------------------------------------------------
// Stage 3: rho[b,n] = sum_k h[b,k] * rho_table[n,k]
// Each wave: 16 batches x 64 n (4 MFMAs). Grid: (ceil(20000/64)=313, 16).
// ---------------------------------------------------------------------------
__global__ __launch_bounds__(256) void rho_kernel(
    const unsigned short* __restrict__ h,     // [BATCH][NH] bf16 (ws)
    const float*          __restrict__ rtab,  // [NG][NH] fp32
    float*                __restrict__ out)   // [BATCH][NG] fp32
{
    const int ng   = blockIdx.x;               // n-group of 64
    const int wave = threadIdx.x >> 6;
    const int lane = threadIdx.x & 63;
    const int l15  = lane & 15;
    const int quad = lane >> 4;
    const int b0   = blockIdx.y * 64 + wave * 16;

    short8 af = *(const short8*)(h + (b0 + l15) * NH + quad * 8);

    #pragma unroll
    for (int t = 0; t < 4; ++t) {
        const int n0 = ng * 64 + t * 16;
        if (n0 >= NG) break;
        // B[k][n] = rtab[n][k]: lane n = n0+l15, k = quad*8+j -> 32B contiguous
        const float* rp = rtab + (long long)(n0 + l15) * NH + quad * 8;
        short8 bfr;
        #pragma unroll
        for (int j = 0; j < 8; ++j)
            bfr[j] = (short)f2bf(rp[j]);
        f32x4 acc = {0.f, 0.f, 0.f, 0.f};
        acc = __builtin_amdgcn_mfma_f32_16x16x32_bf16(af, bfr, acc, 0, 0, 0);
        #pragma unroll
        for (int r = 0; r < 4; ++r) {
            int b = b0 + quad * 4 + r;
            out[(long long)b * NG + n0 + l15] = acc[r];
        }
    }
}

extern "C" void kernel_launch(void* const* d_in, const int* in_sizes, int n_in,
                              void* d_out, int out_size, void* d_ws, size_t ws_size,
                              hipStream_t stream) {
    const float* latent = (const float*)d_in[0];
    const int*   genes  = (const int*)d_in[1];
    const float* W      = (const float*)d_in[2];
    const float* bias   = (const float*)d_in[3];
    const float* gamma  = (const float*)d_in[4];
    const float* beta   = (const float*)d_in[5];
    const float* mean   = (const float*)d_in[6];
    const float* var    = (const float*)d_in[7];
    const float* ltab   = (const float*)d_in[8];
    const float* rtab   = (const float*)d_in[9];

    float* out = (float*)d_out;
    unsigned short* h = (unsigned short*)d_ws;   // 1024*32*2 = 64 KB

    // logit occupies the first BATCH*GOI*NC floats of d_out, rho follows.
    float* out_logit = out;
    float* out_rho   = out + (long long)BATCH * GOI * NC;

    h_kernel<<<dim3((BATCH * NH) / 256), 256, 0, stream>>>(
        latent, W, bias, gamma, beta, mean, var, h);

    logit_kernel<<<dim3(GOI, 4), 256, 0, stream>>>(h, ltab, genes, out_logit);

    rho_kernel<<<dim3((NG + 63) / 64, BATCH / 64), 256, 0, stream>>>(
        h, rtab, out_rho);
}